// Round 15
// baseline (184.831 us; speedup 1.0000x reference)
//
#include <hip/hip_runtime.h>
#include <math.h>

#define DD    256
#define PLQ   65536           // plane elems (u16) = 256*256
#define SLOTB 131072          // complex slot elems (u16): re plane + im plane
#define NTS   128
#define DT_C  0.02f

typedef unsigned short u16;
typedef unsigned int   u32;
typedef __attribute__((ext_vector_type(8))) short s16x8;
typedef __attribute__((ext_vector_type(4))) float f32x4;

typedef __attribute__((address_space(1))) const unsigned int GU32;
typedef __attribute__((address_space(3))) unsigned int LU32;

// Plane = [64 rows][128B = 64 k-elems x 2B], XOR-swizzled. Involution.
__device__ __forceinline__ u32 swzB(u32 b) {
    return b ^ (((((b >> 7) ^ (b >> 10)) & 7u)) << 4);
}
__device__ __forceinline__ u16 f2bf(float f) {
    u32 u = __float_as_uint(f);
    return (u16)((u + 0x7FFFu + ((u >> 16) & 1u)) >> 16);
}
__device__ __forceinline__ float bf2f(u16 h) {
    return __uint_as_float(((u32)h) << 16);
}
__device__ __forceinline__ void gll16(const u16* g, char* ldsBase, u32 ldsByteOff) {
    u32 off = (u32)__builtin_amdgcn_readfirstlane((int)ldsByteOff);
    __builtin_amdgcn_global_load_lds((GU32*)g, (LU32*)(ldsBase + off), 16, 0, 0);
}

// ---------------------------------------------------------------------------
// build: X = DT * A_ts (bf16, N-layout only, float4 reads, no LDS).
// ---------------------------------------------------------------------------
__global__ __launch_bounds__(256)
void build_kernel(const float* __restrict__ cr, const float* __restrict__ ci,
                  const float* __restrict__ dre, const float* __restrict__ dimg,
                  const float* __restrict__ gre, const float* __restrict__ gim,
                  u16* __restrict__ Xn, int ts0)
{
    const int ts = blockIdx.y;
    const int k  = ts0 + ts;
    const int i4 = (blockIdx.x * 256 + threadIdx.x) * 4;   // 0..PLQ-4

    const float c0f = cr[2*k], c1f = cr[2*k+1];
    const float e0f = ci[2*k], e1f = ci[2*k+1];

    const float4 g0r = *(const float4*)&gre[0*PLQ + i4];
    const float4 g1r = *(const float4*)&gre[1*PLQ + i4];
    const float4 g2r = *(const float4*)&gre[2*PLQ + i4];
    const float4 g3r = *(const float4*)&gre[3*PLQ + i4];
    const float4 g0i = *(const float4*)&gim[0*PLQ + i4];
    const float4 g1i = *(const float4*)&gim[1*PLQ + i4];
    const float4 g2i = *(const float4*)&gim[2*PLQ + i4];
    const float4 g3i = *(const float4*)&gim[3*PLQ + i4];
    const float4 d_r = *(const float4*)&dre[i4];
    const float4 d_i = *(const float4*)&dimg[i4];
    const float* gr00 = &g0r.x; const float* gr01 = &g1r.x;
    const float* gr10 = &g2r.x; const float* gr11 = &g3r.x;
    const float* gi00 = &g0i.x; const float* gi01 = &g1i.x;
    const float* gi10 = &g2i.x; const float* gi11 = &g3i.x;
    const float* dr4  = &d_r.x; const float* di4  = &d_i.x;

    ushort4 hr, hi;
    u16* hrp = &hr.x; u16* hip = &hi.x;
    #pragma unroll
    for (int j = 0; j < 4; ++j) {
        const float are = dr4[j] + c0f*(gr00[j]+gr01[j]) + c1f*(gr10[j]+gr11[j])
                                 - e0f*(gi00[j]-gi01[j]) - e1f*(gi10[j]-gi11[j]);
        const float aim = di4[j] + c0f*(gi00[j]+gi01[j]) + c1f*(gi10[j]+gi11[j])
                                 + e0f*(gr00[j]-gr01[j]) + e1f*(gr10[j]-gr11[j]);
        hrp[j] = f2bf(DT_C * are);
        hip[j] = f2bf(DT_C * aim);
    }
    u16* X = Xn + (size_t)ts * SLOTB;
    *(ushort4*)&X[i4]       = hr;
    *(ushort4*)&X[PLQ + i4] = hi;
}

// ---------------------------------------------------------------------------
// Batched complex bf16 MFMA GEMM, 64x64 tile, 4 waves, BK=64, single 32 KB
// buffer + vectorized LDS-bounce epilogue (round-14 proven).
// __launch_bounds__(256,8) forces VGPR<=64 -> 5 resident blocks/CU (LDS cap).
//   out = aN*(A@B) + bN1*X1 + bN2*X2
// ---------------------------------------------------------------------------
__global__ __launch_bounds__(256, 8)
void cgemm64(const u16* __restrict__ Ab, const u16* __restrict__ Bb,
             u16* __restrict__ outN,
             const u16* __restrict__ X1b, const u16* __restrict__ X2b,
             float aN, float bN1, float bN2,
             int aS, int aO, int bS, int bO, int cS, int cO,
             int x1S, int x1O, int x2S, int x2O)
{
    __shared__ char lds[32768];

    // ---- bijective XCD-chunked block swizzle (nwg = 16*nz, always %8==0) ----
    const u32 nwg = 16u * (u32)gridDim.z;
    const u32 wg  = (u32)blockIdx.x + 4u*(u32)blockIdx.y + 16u*(u32)blockIdx.z;
    const u32 q   = nwg >> 3;
    const u32 w   = (wg & 7u) * q + (wg >> 3);
    const int bn = (int)(w & 3u) * 64;
    const int bm = (int)((w >> 2) & 3u) * 64;
    const int z  = (int)(w >> 4);

    const u16* __restrict__ A = Ab + (size_t)(z*aS + aO) * SLOTB;
    const u16* __restrict__ B = Bb + (size_t)(z*bS + bO) * SLOTB;

    const int t = threadIdx.x;

    // gll16 staging: plane-local dest byte b in {t*16, 4096+t*16};
    // source logical byte L = swzB(b) -> row = L>>7, k-elem = (L&127)>>1.
    const u32 b0 = (u32)t * 16u, b1 = 4096u + (u32)t * 16u;
    const u32 L0 = swzB(b0),     L1 = swzB(b1);
    const int rA0 = (int)(L0 >> 7), kA0 = (int)((L0 & 127u) >> 1);
    const int rA1 = (int)(L1 >> 7), kA1 = (int)((L1 & 127u) >> 1);
    const u32 wvoff = ((u32)(t >> 6)) * 1024u;

    const u16* pA0 = A + (size_t)(bm + rA0)*DD + kA0;
    const u16* pA1 = A + (size_t)(bm + rA1)*DD + kA1;

    // B scatter mapping (N-layout [k][n])
    const int kRow = t >> 3;                   // 0..31
    const int nCh  = t & 7;                    // n0 = nCh*8

    const int wv = t >> 6, ln = t & 63;
    const int wrow = (wv >> 1) * 32, wcol = (wv & 1) * 32;
    const int lg = ln >> 4, lc = ln & 15;

    f32x4 accR[2][2], accI[2][2];
    #pragma unroll
    for (int i = 0; i < 2; ++i)
        #pragma unroll
        for (int j = 0; j < 2; ++j) {
            accR[i][j] = (f32x4){0.f,0.f,0.f,0.f};
            accI[i][j] = (f32x4){0.f,0.f,0.f,0.f};
        }

    // ---- prologue: stage K-tile 0 ----
    {
        gll16(pA0,       lds, wvoff +     0u);
        gll16(pA1,       lds, wvoff +  4096u);
        gll16(pA0 + PLQ, lds, wvoff +  8192u);
        gll16(pA1 + PLQ, lds, wvoff + 12288u);
        #pragma unroll
        for (int h = 0; h < 2; ++h) {
            const int kk = h*32 + kRow;
            const s16x8 vr = *(const s16x8*)(B +       (size_t)kk*DD + bn + nCh*8);
            const s16x8 vi = *(const s16x8*)(B + PLQ + (size_t)kk*DD + bn + nCh*8);
            #pragma unroll
            for (int e = 0; e < 8; ++e) {
                const u32 off = swzB((u32)(nCh*8 + e)*128u + (u32)kk*2u);
                *(u16*)(lds + 16384 + off) = (u16)vr[e];
                *(u16*)(lds + 24576 + off) = (u16)vi[e];
            }
        }
    }
    __syncthreads();

    // ---- main loop: 4 K-phases ----
    for (int it = 0; it < 4; ++it) {
        s16x8 nvr0, nvi0, nvr1, nvi1;
        if (it < 3) {                          // prefetch next B tile to regs
            const int k1 = 64*(it + 1);
            nvr0 = *(const s16x8*)(B +       (size_t)(k1 + kRow)*DD + bn + nCh*8);
            nvi0 = *(const s16x8*)(B + PLQ + (size_t)(k1 + kRow)*DD + bn + nCh*8);
            nvr1 = *(const s16x8*)(B +       (size_t)(k1 + 32 + kRow)*DD + bn + nCh*8);
            nvi1 = *(const s16x8*)(B + PLQ + (size_t)(k1 + 32 + kRow)*DD + bn + nCh*8);
        }

        #pragma unroll
        for (int s = 0; s < 2; ++s) {          // two K=32 sub-steps
            s16x8 ar[2], ai[2], br[2], bi[2];
            #pragma unroll
            for (int fm = 0; fm < 2; ++fm) {
                const u32 so = swzB((u32)(wrow + fm*16 + lc)*128u + (u32)(s*4 + lg)*16u);
                ar[fm] = *(const s16x8*)(lds + so);
                ai[fm] = *(const s16x8*)(lds + 8192 + so);
            }
            #pragma unroll
            for (int fn = 0; fn < 2; ++fn) {
                const u32 so = swzB((u32)(wcol + fn*16 + lc)*128u + (u32)(s*4 + lg)*16u);
                br[fn] = *(const s16x8*)(lds + 16384 + so);
                bi[fn] = *(const s16x8*)(lds + 24576 + so);
            }
            #pragma unroll
            for (int fm = 0; fm < 2; ++fm)
                #pragma unroll
                for (int fn = 0; fn < 2; ++fn) {
                    accI[fm][fn] = __builtin_amdgcn_mfma_f32_16x16x32_bf16(ar[fm], bi[fn], accI[fm][fn], 0, 0, 0);
                    accI[fm][fn] = __builtin_amdgcn_mfma_f32_16x16x32_bf16(ai[fm], br[fn], accI[fm][fn], 0, 0, 0);
                }
            #pragma unroll
            for (int fm = 0; fm < 2; ++fm) ai[fm] ^= (short)0x8000u;
            #pragma unroll
            for (int fm = 0; fm < 2; ++fm)
                #pragma unroll
                for (int fn = 0; fn < 2; ++fn) {
                    accR[fm][fn] = __builtin_amdgcn_mfma_f32_16x16x32_bf16(ar[fm], br[fn], accR[fm][fn], 0, 0, 0);
                    accR[fm][fn] = __builtin_amdgcn_mfma_f32_16x16x32_bf16(ai[fm], bi[fn], accR[fm][fn], 0, 0, 0);
                }
        }

        if (it < 3) {
            const int k1 = 64*(it + 1);
            __syncthreads();                   // everyone done reading buffer
            gll16(pA0 + k1,       lds, wvoff +     0u);
            gll16(pA1 + k1,       lds, wvoff +  4096u);
            gll16(pA0 + PLQ + k1, lds, wvoff +  8192u);
            gll16(pA1 + PLQ + k1, lds, wvoff + 12288u);
            #pragma unroll
            for (int e = 0; e < 8; ++e) {
                const u32 off0 = swzB((u32)(nCh*8 + e)*128u + (u32)kRow*2u);
                const u32 off1 = swzB((u32)(nCh*8 + e)*128u + (u32)(32 + kRow)*2u);
                *(u16*)(lds + 16384 + off0) = (u16)nvr0[e];
                *(u16*)(lds + 24576 + off0) = (u16)nvi0[e];
                *(u16*)(lds + 16384 + off1) = (u16)nvr1[e];
                *(u16*)(lds + 24576 + off1) = (u16)nvi1[e];
            }
            __syncthreads();                   // buffer ready
        }
    }

    // ---- vectorized epilogue via LDS bounce ----
    __syncthreads();                           // all waves done with operands
    #pragma unroll
    for (int fm = 0; fm < 2; ++fm)
        #pragma unroll
        for (int fn = 0; fn < 2; ++fn) {
            const int rb = wrow + fm*16 + lg*4;    // local row
            const int c  = wcol + fn*16 + lc;      // local col
            #pragma unroll
            for (int j = 0; j < 4; ++j) {
                const u32 ob = swzB((u32)(rb + j)*128u + (u32)c*2u);
                *(u16*)(lds +        ob) = f2bf(aN * accR[fm][fn][j]);
                *(u16*)(lds + 8192 + ob) = f2bf(aN * accI[fm][fn][j]);
            }
        }
    __syncthreads();

    u16* oN = outN + (size_t)(z*cS + cO) * SLOTB;
    const u16* x1 = X1b ? X1b + (size_t)(z*x1S + x1O) * SLOTB : nullptr;
    const u16* x2 = X2b ? X2b + (size_t)(z*x2S + x2O) * SLOTB : nullptr;

    const int orow = t >> 2;
    const u32 och  = ((u32)t & 3u) * 32u;
    const size_t gOff = (size_t)(bm + orow)*DD + bn + (och >> 1);

    #pragma unroll
    for (int pl = 0; pl < 2; ++pl) {
        const u32 lb   = (u32)pl * 8192u + (u32)orow * 128u + och;
        const size_t g = gOff + (size_t)pl * PLQ;
        #pragma unroll
        for (int h = 0; h < 2; ++h) {
            const s16x8 cv = *(const s16x8*)(lds + swzB(lb + (u32)h*16u));
            float o[8];
            #pragma unroll
            for (int e = 0; e < 8; ++e) o[e] = bf2f((u16)cv[e]);
            if (x1) {
                const s16x8 xv = *(const s16x8*)(x1 + g + h*8);
                #pragma unroll
                for (int e = 0; e < 8; ++e) o[e] += bN1 * bf2f((u16)xv[e]);
            }
            if (x2) {
                const s16x8 xv = *(const s16x8*)(x2 + g + h*8);
                #pragma unroll
                for (int e = 0; e < 8; ++e) o[e] += bN2 * bf2f((u16)xv[e]);
            }
            s16x8 ov;
            #pragma unroll
            for (int e = 0; e < 8; ++e) ov[e] = (short)f2bf(o[e]);
            *(s16x8*)(oN + g + h*8) = ov;
        }
    }
}

// ---------------------------------------------------------------------------
// final4: chain nE deviation matvecs v=(I+E_j)v (4 threads/row, 64-k slices),
// then trace-normalize + fid. 1024 threads.
// ---------------------------------------------------------------------------
__global__ __launch_bounds__(1024)
void final4_kernel(const u16* __restrict__ Es, int nE,
                   const float* __restrict__ s0r, const float* __restrict__ s0i,
                   const float* __restrict__ tgr, const float* __restrict__ tgi,
                   float* __restrict__ out, int outSize)
{
    __shared__ float sr[DD], si[DD];
    __shared__ float psr[4][DD], psi[4][DD];
    __shared__ float red[DD];
    __shared__ float cR, cI;

    const int t   = threadIdx.x;
    const int row = t & 255;
    const int qt  = t >> 8;              // 0..3, k-slice [qt*64, qt*64+64)

    if (t < DD) { sr[t] = s0r[t]; si[t] = s0i[t]; }
    __syncthreads();

    for (int j = 0; j < nE; ++j) {
        const u16* Er = Es + (size_t)j*SLOTB + (size_t)row*DD + qt*64;
        const u16* Ei = Er + PLQ;
        float ar = 0.f, ai = 0.f;
        #pragma unroll
        for (int kk = 0; kk < 8; ++kk) {
            const s16x8 er = *(const s16x8*)(Er + kk*8);
            const s16x8 ei = *(const s16x8*)(Ei + kk*8);
            #pragma unroll
            for (int e = 0; e < 8; ++e) {
                const int k = qt*64 + kk*8 + e;
                const float pr = bf2f((u16)er[e]);
                const float pi = bf2f((u16)ei[e]);
                ar += pr*sr[k] - pi*si[k];
                ai += pr*si[k] + pi*sr[k];
            }
        }
        psr[qt][row] = ar; psi[qt][row] = ai;
        __syncthreads();
        float nr = 0.f, ni = 0.f;
        if (t < DD) {
            nr = sr[t] + psr[0][t] + psr[1][t] + psr[2][t] + psr[3][t];
            ni = si[t] + psi[0][t] + psi[1][t] + psi[2][t] + psi[3][t];
        }
        __syncthreads();
        if (t < DD) { sr[t] = nr; si[t] = ni; }
        __syncthreads();
    }

    if (t == 0) {
        float xr = 0.f, xi = 0.f;
        for (int i = 0; i < 16; ++i) { xr += sr[i*17]; xi += si[i*17]; }
        cR = xr; cI = xi;
    }
    __syncthreads();

    const float den = cR*cR + cI*cI;
    float str = 0.f, sti = 0.f;
    if (t < DD) {
        str = (sr[t]*cR + si[t]*cI) / den;
        sti = (si[t]*cR - sr[t]*cI) / den;
        const float dr = str - tgr[t];
        const float di = sti - tgi[t];
        red[t] = dr*dr + di*di;
    }
    __syncthreads();
    for (int s = 128; s > 0; s >>= 1) {
        if (t < s) red[t] += red[t + s];
        __syncthreads();
    }
    const float fid = sqrtf(red[0]);

    if (t < DD) {
        if (outSize >= 2*DD + 1) {
            out[2*t] = str; out[2*t+1] = sti;
            if (t == 0) out[2*DD] = fid;
        } else if (outSize == 2*DD) {
            out[2*t] = str; out[2*t+1] = sti;
        } else {
            out[t] = str;
            if (t == 0 && outSize > DD) out[DD] = fid;
        }
    }
}

// ---------------------------------------------------------------------------
extern "C" void kernel_launch(void* const* d_in, const int* in_sizes, int n_in,
                              void* d_out, int out_size, void* d_ws, size_t ws_size,
                              hipStream_t stream)
{
    (void)in_sizes; (void)n_in;
    const float* cr   = (const float*)d_in[0];
    const float* ci   = (const float*)d_in[1];
    const float* dre  = (const float*)d_in[2];
    const float* dimg = (const float*)d_in[3];
    const float* gre  = (const float*)d_in[4];
    const float* gim  = (const float*)d_in[5];
    const float* s0r  = (const float*)d_in[6];
    const float* s0i  = (const float*)d_in[7];
    const float* tgr  = (const float*)d_in[8];
    const float* tgi  = (const float*)d_in[9];

    // Degree-3 Taylor: E = X + P2/2 + (P2@X)/6, P2 = X@X.
    const float c2 = 0.5f, c3i = 1.f/6.f;

    u16* ws = (u16*)d_ws;
    const long slots = (long)(ws_size / 2) / SLOTB;

    if (slots >= 384) {
        // ============ FAST PATH: z=128, 3 regions, all-N layouts ============
        u16* RX = ws;                      // X (N)
        u16* R1 = ws + 128L * SLOTB;       // P2; tree odd levels
        u16* R2 = ws + 256L * SLOTB;       // E;  tree even levels

        build_kernel<<<dim3(PLQ/1024, 128), 256, 0, stream>>>(
            cr, ci, dre, dimg, gre, gim, RX, 0);

        const dim3 g128(4, 4, 128);
        // G1: P2 = X@X
        cgemm64<<<g128, 256, 0, stream>>>(RX, RX, R1, nullptr, nullptr,
            1.f, 0.f, 0.f,
            1,0, 1,0, 1,0, 0,0, 0,0);
        // G2: E = (P2@X)/6 + X + P2/2 -> R2
        cgemm64<<<g128, 256, 0, stream>>>(R1, RX, R2, RX, R1,
            c3i, 1.f, c2,
            1,0, 1,0, 1,0, 1,0, 1,0);

        // ---- tree: E' = Ea@Eb + Ea + Eb; stop at 4 partials ----
        u16* cur = R2;
        u16* oth = R1;
        for (int n = 128; n > 4; n >>= 1) {
            cgemm64<<<dim3(4, 4, n/2), 256, 0, stream>>>(
                cur, cur, oth, cur, cur,
                1.f, 1.f, 1.f,
                2,1, 2,0, 1,0, 2,1, 2,0);
            u16* tmp = cur; cur = oth; oth = tmp;
        }
        final4_kernel<<<1, 1024, 0, stream>>>(cur, 4, s0r, s0i, tgr, tgi,
                                              (float*)d_out, out_size);
    } else {
        // ============ FALLBACK: chunked (P + 2C regions) ====================
        u16* P  = ws;                      // final E, 128 slots
        u16* CB = ws + 128L * SLOTB;
        int C = (int)((slots - 128) / 2);
        if (C > NTS) C = NTS;
        if (C < 32)  C = 32;               // tree ping needs 2C >= 64

        for (int ts0 = 0; ts0 < NTS; ts0 += C) {
            int nb = NTS - ts0; if (nb > C) nb = C;
            u16* Xn = CB;
            u16* P2 = CB + 1L*C*SLOTB;

            build_kernel<<<dim3(PLQ/1024, nb), 256, 0, stream>>>(
                cr, ci, dre, dimg, gre, gim, Xn, ts0);

            const dim3 grid(4, 4, nb);
            cgemm64<<<grid, 256, 0, stream>>>(Xn, Xn, P2, nullptr, nullptr,
                1.f, 0.f, 0.f,
                1,0, 1,0, 1,0, 0,0, 0,0);
            cgemm64<<<grid, 256, 0, stream>>>(P2, Xn, P, Xn, P2,
                c3i, 1.f, c2,
                1,0, 1,0, 1,ts0, 1,0, 1,0);
        }

        u16* cur = P;
        u16* oth = CB;
        for (int n = 128; n > 4; n >>= 1) {
            cgemm64<<<dim3(4, 4, n/2), 256, 0, stream>>>(
                cur, cur, oth, cur, cur,
                1.f, 1.f, 1.f,
                2,1, 2,0, 1,0, 2,1, 2,0);
            u16* tmp = cur; cur = oth; oth = tmp;
        }
        final4_kernel<<<1, 1024, 0, stream>>>(cur, 4, s0r, s0i, tgr, tgi,
                                              (float*)d_out, out_size);
    }
}

// Round 16
// 174.323 us; speedup vs baseline: 1.0603x; 1.0603x over previous
//
#include <hip/hip_runtime.h>
#include <math.h>

#define DD    256
#define PLQ   65536           // plane elems (u16) = 256*256
#define SLOTB 131072          // complex slot elems (u16): re plane + im plane
#define NTS   128
#define DT_C  0.02f

typedef unsigned short u16;
typedef unsigned int   u32;
typedef __attribute__((ext_vector_type(8))) short s16x8;
typedef __attribute__((ext_vector_type(4))) float f32x4;

typedef __attribute__((address_space(1))) const unsigned int GU32;
typedef __attribute__((address_space(3))) unsigned int LU32;

// Plane = [64 rows][128B = 64 k-elems x 2B], XOR-swizzled. Involution.
__device__ __forceinline__ u32 swzB(u32 b) {
    return b ^ (((((b >> 7) ^ (b >> 10)) & 7u)) << 4);
}
__device__ __forceinline__ u16 f2bf(float f) {
    u32 u = __float_as_uint(f);
    return (u16)((u + 0x7FFFu + ((u >> 16) & 1u)) >> 16);
}
__device__ __forceinline__ float bf2f(u16 h) {
    return __uint_as_float(((u32)h) << 16);
}
__device__ __forceinline__ void gll16(const u16* g, char* ldsBase, u32 ldsByteOff) {
    u32 off = (u32)__builtin_amdgcn_readfirstlane((int)ldsByteOff);
    __builtin_amdgcn_global_load_lds((GU32*)g, (LU32*)(ldsBase + off), 16, 0, 0);
}

// ---------------------------------------------------------------------------
// build: X = DT * A_ts (bf16, N-layout only, float4 reads, no LDS).
// ---------------------------------------------------------------------------
__global__ __launch_bounds__(256)
void build_kernel(const float* __restrict__ cr, const float* __restrict__ ci,
                  const float* __restrict__ dre, const float* __restrict__ dimg,
                  const float* __restrict__ gre, const float* __restrict__ gim,
                  u16* __restrict__ Xn, int ts0)
{
    const int ts = blockIdx.y;
    const int k  = ts0 + ts;
    const int i4 = (blockIdx.x * 256 + threadIdx.x) * 4;   // 0..PLQ-4

    const float c0f = cr[2*k], c1f = cr[2*k+1];
    const float e0f = ci[2*k], e1f = ci[2*k+1];

    const float4 g0r = *(const float4*)&gre[0*PLQ + i4];
    const float4 g1r = *(const float4*)&gre[1*PLQ + i4];
    const float4 g2r = *(const float4*)&gre[2*PLQ + i4];
    const float4 g3r = *(const float4*)&gre[3*PLQ + i4];
    const float4 g0i = *(const float4*)&gim[0*PLQ + i4];
    const float4 g1i = *(const float4*)&gim[1*PLQ + i4];
    const float4 g2i = *(const float4*)&gim[2*PLQ + i4];
    const float4 g3i = *(const float4*)&gim[3*PLQ + i4];
    const float4 d_r = *(const float4*)&dre[i4];
    const float4 d_i = *(const float4*)&dimg[i4];
    const float* gr00 = &g0r.x; const float* gr01 = &g1r.x;
    const float* gr10 = &g2r.x; const float* gr11 = &g3r.x;
    const float* gi00 = &g0i.x; const float* gi01 = &g1i.x;
    const float* gi10 = &g2i.x; const float* gi11 = &g3i.x;
    const float* dr4  = &d_r.x; const float* di4  = &d_i.x;

    ushort4 hr, hi;
    u16* hrp = &hr.x; u16* hip = &hi.x;
    #pragma unroll
    for (int j = 0; j < 4; ++j) {
        const float are = dr4[j] + c0f*(gr00[j]+gr01[j]) + c1f*(gr10[j]+gr11[j])
                                 - e0f*(gi00[j]-gi01[j]) - e1f*(gi10[j]-gi11[j]);
        const float aim = di4[j] + c0f*(gi00[j]+gi01[j]) + c1f*(gi10[j]+gi11[j])
                                 + e0f*(gr00[j]-gr01[j]) + e1f*(gr10[j]-gr11[j]);
        hrp[j] = f2bf(DT_C * are);
        hip[j] = f2bf(DT_C * aim);
    }
    u16* X = Xn + (size_t)ts * SLOTB;
    *(ushort4*)&X[i4]       = hr;
    *(ushort4*)&X[PLQ + i4] = hi;
}

// ---------------------------------------------------------------------------
// Batched complex bf16 MFMA GEMM, 64x64 tile, 4 waves, BK=64, single 32 KB
// buffer + vectorized LDS-bounce epilogue (round-14 proven).
// __launch_bounds__(256,8) forces VGPR<=64 -> 5 resident blocks/CU (LDS cap).
//   out = aN*(A@B) + bN1*X1 + bN2*X2
// ---------------------------------------------------------------------------
__global__ __launch_bounds__(256, 8)
void cgemm64(const u16* __restrict__ Ab, const u16* __restrict__ Bb,
             u16* __restrict__ outN,
             const u16* __restrict__ X1b, const u16* __restrict__ X2b,
             float aN, float bN1, float bN2,
             int aS, int aO, int bS, int bO, int cS, int cO,
             int x1S, int x1O, int x2S, int x2O)
{
    __shared__ char lds[32768];

    // ---- bijective XCD-chunked block swizzle (nwg = 16*nz, always %8==0) ----
    const u32 nwg = 16u * (u32)gridDim.z;
    const u32 wg  = (u32)blockIdx.x + 4u*(u32)blockIdx.y + 16u*(u32)blockIdx.z;
    const u32 q   = nwg >> 3;
    const u32 w   = (wg & 7u) * q + (wg >> 3);
    const int bn = (int)(w & 3u) * 64;
    const int bm = (int)((w >> 2) & 3u) * 64;
    const int z  = (int)(w >> 4);

    const u16* __restrict__ A = Ab + (size_t)(z*aS + aO) * SLOTB;
    const u16* __restrict__ B = Bb + (size_t)(z*bS + bO) * SLOTB;

    const int t = threadIdx.x;

    // gll16 staging: plane-local dest byte b in {t*16, 4096+t*16};
    // source logical byte L = swzB(b) -> row = L>>7, k-elem = (L&127)>>1.
    const u32 b0 = (u32)t * 16u, b1 = 4096u + (u32)t * 16u;
    const u32 L0 = swzB(b0),     L1 = swzB(b1);
    const int rA0 = (int)(L0 >> 7), kA0 = (int)((L0 & 127u) >> 1);
    const int rA1 = (int)(L1 >> 7), kA1 = (int)((L1 & 127u) >> 1);
    const u32 wvoff = ((u32)(t >> 6)) * 1024u;

    const u16* pA0 = A + (size_t)(bm + rA0)*DD + kA0;
    const u16* pA1 = A + (size_t)(bm + rA1)*DD + kA1;

    // B scatter mapping (N-layout [k][n])
    const int kRow = t >> 3;                   // 0..31
    const int nCh  = t & 7;                    // n0 = nCh*8

    const int wv = t >> 6, ln = t & 63;
    const int wrow = (wv >> 1) * 32, wcol = (wv & 1) * 32;
    const int lg = ln >> 4, lc = ln & 15;

    f32x4 accR[2][2], accI[2][2];
    #pragma unroll
    for (int i = 0; i < 2; ++i)
        #pragma unroll
        for (int j = 0; j < 2; ++j) {
            accR[i][j] = (f32x4){0.f,0.f,0.f,0.f};
            accI[i][j] = (f32x4){0.f,0.f,0.f,0.f};
        }

    // ---- prologue: stage K-tile 0 ----
    {
        gll16(pA0,       lds, wvoff +     0u);
        gll16(pA1,       lds, wvoff +  4096u);
        gll16(pA0 + PLQ, lds, wvoff +  8192u);
        gll16(pA1 + PLQ, lds, wvoff + 12288u);
        #pragma unroll
        for (int h = 0; h < 2; ++h) {
            const int kk = h*32 + kRow;
            const s16x8 vr = *(const s16x8*)(B +       (size_t)kk*DD + bn + nCh*8);
            const s16x8 vi = *(const s16x8*)(B + PLQ + (size_t)kk*DD + bn + nCh*8);
            #pragma unroll
            for (int e = 0; e < 8; ++e) {
                const u32 off = swzB((u32)(nCh*8 + e)*128u + (u32)kk*2u);
                *(u16*)(lds + 16384 + off) = (u16)vr[e];
                *(u16*)(lds + 24576 + off) = (u16)vi[e];
            }
        }
    }
    __syncthreads();

    // ---- main loop: 4 K-phases ----
    for (int it = 0; it < 4; ++it) {
        s16x8 nvr0, nvi0, nvr1, nvi1;
        if (it < 3) {                          // prefetch next B tile to regs
            const int k1 = 64*(it + 1);
            nvr0 = *(const s16x8*)(B +       (size_t)(k1 + kRow)*DD + bn + nCh*8);
            nvi0 = *(const s16x8*)(B + PLQ + (size_t)(k1 + kRow)*DD + bn + nCh*8);
            nvr1 = *(const s16x8*)(B +       (size_t)(k1 + 32 + kRow)*DD + bn + nCh*8);
            nvi1 = *(const s16x8*)(B + PLQ + (size_t)(k1 + 32 + kRow)*DD + bn + nCh*8);
        }

        #pragma unroll
        for (int s = 0; s < 2; ++s) {          // two K=32 sub-steps
            s16x8 ar[2], ai[2], br[2], bi[2];
            #pragma unroll
            for (int fm = 0; fm < 2; ++fm) {
                const u32 so = swzB((u32)(wrow + fm*16 + lc)*128u + (u32)(s*4 + lg)*16u);
                ar[fm] = *(const s16x8*)(lds + so);
                ai[fm] = *(const s16x8*)(lds + 8192 + so);
            }
            #pragma unroll
            for (int fn = 0; fn < 2; ++fn) {
                const u32 so = swzB((u32)(wcol + fn*16 + lc)*128u + (u32)(s*4 + lg)*16u);
                br[fn] = *(const s16x8*)(lds + 16384 + so);
                bi[fn] = *(const s16x8*)(lds + 24576 + so);
            }
            #pragma unroll
            for (int fm = 0; fm < 2; ++fm)
                #pragma unroll
                for (int fn = 0; fn < 2; ++fn) {
                    accI[fm][fn] = __builtin_amdgcn_mfma_f32_16x16x32_bf16(ar[fm], bi[fn], accI[fm][fn], 0, 0, 0);
                    accI[fm][fn] = __builtin_amdgcn_mfma_f32_16x16x32_bf16(ai[fm], br[fn], accI[fm][fn], 0, 0, 0);
                }
            #pragma unroll
            for (int fm = 0; fm < 2; ++fm) ai[fm] ^= (short)0x8000u;
            #pragma unroll
            for (int fm = 0; fm < 2; ++fm)
                #pragma unroll
                for (int fn = 0; fn < 2; ++fn) {
                    accR[fm][fn] = __builtin_amdgcn_mfma_f32_16x16x32_bf16(ar[fm], br[fn], accR[fm][fn], 0, 0, 0);
                    accR[fm][fn] = __builtin_amdgcn_mfma_f32_16x16x32_bf16(ai[fm], bi[fn], accR[fm][fn], 0, 0, 0);
                }
        }

        if (it < 3) {
            const int k1 = 64*(it + 1);
            __syncthreads();                   // everyone done reading buffer
            gll16(pA0 + k1,       lds, wvoff +     0u);
            gll16(pA1 + k1,       lds, wvoff +  4096u);
            gll16(pA0 + PLQ + k1, lds, wvoff +  8192u);
            gll16(pA1 + PLQ + k1, lds, wvoff + 12288u);
            #pragma unroll
            for (int e = 0; e < 8; ++e) {
                const u32 off0 = swzB((u32)(nCh*8 + e)*128u + (u32)kRow*2u);
                const u32 off1 = swzB((u32)(nCh*8 + e)*128u + (u32)(32 + kRow)*2u);
                *(u16*)(lds + 16384 + off0) = (u16)nvr0[e];
                *(u16*)(lds + 24576 + off0) = (u16)nvi0[e];
                *(u16*)(lds + 16384 + off1) = (u16)nvr1[e];
                *(u16*)(lds + 24576 + off1) = (u16)nvi1[e];
            }
            __syncthreads();                   // buffer ready
        }
    }

    // ---- vectorized epilogue via LDS bounce ----
    __syncthreads();                           // all waves done with operands
    #pragma unroll
    for (int fm = 0; fm < 2; ++fm)
        #pragma unroll
        for (int fn = 0; fn < 2; ++fn) {
            const int rb = wrow + fm*16 + lg*4;    // local row
            const int c  = wcol + fn*16 + lc;      // local col
            #pragma unroll
            for (int j = 0; j < 4; ++j) {
                const u32 ob = swzB((u32)(rb + j)*128u + (u32)c*2u);
                *(u16*)(lds +        ob) = f2bf(aN * accR[fm][fn][j]);
                *(u16*)(lds + 8192 + ob) = f2bf(aN * accI[fm][fn][j]);
            }
        }
    __syncthreads();

    u16* oN = outN + (size_t)(z*cS + cO) * SLOTB;
    const u16* x1 = X1b ? X1b + (size_t)(z*x1S + x1O) * SLOTB : nullptr;
    const u16* x2 = X2b ? X2b + (size_t)(z*x2S + x2O) * SLOTB : nullptr;

    const int orow = t >> 2;
    const u32 och  = ((u32)t & 3u) * 32u;
    const size_t gOff = (size_t)(bm + orow)*DD + bn + (och >> 1);

    #pragma unroll
    for (int pl = 0; pl < 2; ++pl) {
        const u32 lb   = (u32)pl * 8192u + (u32)orow * 128u + och;
        const size_t g = gOff + (size_t)pl * PLQ;
        #pragma unroll
        for (int h = 0; h < 2; ++h) {
            const s16x8 cv = *(const s16x8*)(lds + swzB(lb + (u32)h*16u));
            float o[8];
            #pragma unroll
            for (int e = 0; e < 8; ++e) o[e] = bf2f((u16)cv[e]);
            if (x1) {
                const s16x8 xv = *(const s16x8*)(x1 + g + h*8);
                #pragma unroll
                for (int e = 0; e < 8; ++e) o[e] += bN1 * bf2f((u16)xv[e]);
            }
            if (x2) {
                const s16x8 xv = *(const s16x8*)(x2 + g + h*8);
                #pragma unroll
                for (int e = 0; e < 8; ++e) o[e] += bN2 * bf2f((u16)xv[e]);
            }
            s16x8 ov;
            #pragma unroll
            for (int e = 0; e < 8; ++e) ov[e] = (short)f2bf(o[e]);
            *(s16x8*)(oN + g + h*8) = ov;
        }
    }
}

// ---------------------------------------------------------------------------
// final: v = s0 + Etot@s0 ; c = sum(v[diag]) ; sT = v/c ; fid = ||sT-tgt||_F
// ---------------------------------------------------------------------------
__global__ __launch_bounds__(256)
void final_kernel(const u16* __restrict__ Et,
                  const float* __restrict__ s0r, const float* __restrict__ s0i,
                  const float* __restrict__ tgr, const float* __restrict__ tgi,
                  float* __restrict__ out, int outSize)
{
    __shared__ float sr[DD], si[DD], red[DD];
    __shared__ float cR, cI;
    const int t = threadIdx.x;
    sr[t] = s0r[t];
    si[t] = s0i[t];
    __syncthreads();

    const u16* Er = Et + (size_t)t*DD;
    const u16* Ei = Er + PLQ;
    float ar = sr[t], ai = si[t];
    for (int kk = 0; kk < DD/8; ++kk) {
        const s16x8 er = *(const s16x8*)(Er + kk*8);
        const s16x8 ei = *(const s16x8*)(Ei + kk*8);
        #pragma unroll
        for (int jj = 0; jj < 8; ++jj) {
            const float pr = bf2f((u16)er[jj]);
            const float pi = bf2f((u16)ei[jj]);
            const int k = kk*8 + jj;
            ar += pr*sr[k] - pi*si[k];
            ai += pr*si[k] + pi*sr[k];
        }
    }
    __syncthreads();
    sr[t] = ar; si[t] = ai;
    __syncthreads();

    if (t == 0) {
        float xr = 0.f, xi = 0.f;
        for (int i = 0; i < 16; ++i) { xr += sr[i*17]; xi += si[i*17]; }
        cR = xr; cI = xi;
    }
    __syncthreads();

    const float den = cR*cR + cI*cI;
    const float str = (ar*cR + ai*cI) / den;
    const float sti = (ai*cR - ar*cI) / den;

    const float dr = str - tgr[t];
    const float di = sti - tgi[t];
    red[t] = dr*dr + di*di;
    __syncthreads();
    for (int s = 128; s > 0; s >>= 1) {
        if (t < s) red[t] += red[t + s];
        __syncthreads();
    }
    const float fid = sqrtf(red[0]);

    if (outSize >= 2*DD + 1) {
        out[2*t] = str; out[2*t+1] = sti;
        if (t == 0) out[2*DD] = fid;
    } else if (outSize == 2*DD) {
        out[2*t] = str; out[2*t+1] = sti;
    } else {
        out[t] = str;
        if (t == 0 && outSize > DD) out[DD] = fid;
    }
}

// ---------------------------------------------------------------------------
extern "C" void kernel_launch(void* const* d_in, const int* in_sizes, int n_in,
                              void* d_out, int out_size, void* d_ws, size_t ws_size,
                              hipStream_t stream)
{
    (void)in_sizes; (void)n_in;
    const float* cr   = (const float*)d_in[0];
    const float* ci   = (const float*)d_in[1];
    const float* dre  = (const float*)d_in[2];
    const float* dimg = (const float*)d_in[3];
    const float* gre  = (const float*)d_in[4];
    const float* gim  = (const float*)d_in[5];
    const float* s0r  = (const float*)d_in[6];
    const float* s0i  = (const float*)d_in[7];
    const float* tgr  = (const float*)d_in[8];
    const float* tgi  = (const float*)d_in[9];

    // Degree-3 Taylor: E = X + P2/2 + (P2@X)/6, P2 = X@X.
    const float c2 = 0.5f, c3i = 1.f/6.f;

    u16* ws = (u16*)d_ws;
    const long slots = (long)(ws_size / 2) / SLOTB;

    if (slots >= 384) {
        // ============ FAST PATH: z=128, 3 regions, all-N layouts ============
        u16* RX = ws;                      // X (N)
        u16* R1 = ws + 128L * SLOTB;       // P2; tree odd levels
        u16* R2 = ws + 256L * SLOTB;       // E;  tree even levels

        build_kernel<<<dim3(PLQ/1024, 128), 256, 0, stream>>>(
            cr, ci, dre, dimg, gre, gim, RX, 0);

        const dim3 g128(4, 4, 128);
        // G1: P2 = X@X
        cgemm64<<<g128, 256, 0, stream>>>(RX, RX, R1, nullptr, nullptr,
            1.f, 0.f, 0.f,
            1,0, 1,0, 1,0, 0,0, 0,0);
        // G2: E = (P2@X)/6 + X + P2/2 -> R2
        cgemm64<<<g128, 256, 0, stream>>>(R1, RX, R2, RX, R1,
            c3i, 1.f, c2,
            1,0, 1,0, 1,0, 1,0, 1,0);

        // ---- tree: E' = Ea@Eb + Ea + Eb (all N-layout) ----
        u16* cur = R2;
        u16* oth = R1;
        for (int n = 128; n > 1; n >>= 1) {
            cgemm64<<<dim3(4, 4, n/2), 256, 0, stream>>>(
                cur, cur, oth, cur, cur,
                1.f, 1.f, 1.f,
                2,1, 2,0, 1,0, 2,1, 2,0);
            u16* tmp = cur; cur = oth; oth = tmp;
        }
        final_kernel<<<1, 256, 0, stream>>>(cur, s0r, s0i, tgr, tgi,
                                            (float*)d_out, out_size);
    } else {
        // ============ FALLBACK: chunked (P + 2C regions) ====================
        u16* P  = ws;                      // final E, 128 slots
        u16* CB = ws + 128L * SLOTB;
        int C = (int)((slots - 128) / 2);
        if (C > NTS) C = NTS;
        if (C < 32)  C = 32;               // tree ping needs 2C >= 64

        for (int ts0 = 0; ts0 < NTS; ts0 += C) {
            int nb = NTS - ts0; if (nb > C) nb = C;
            u16* Xn = CB;
            u16* P2 = CB + 1L*C*SLOTB;

            build_kernel<<<dim3(PLQ/1024, nb), 256, 0, stream>>>(
                cr, ci, dre, dimg, gre, gim, Xn, ts0);

            const dim3 grid(4, 4, nb);
            cgemm64<<<grid, 256, 0, stream>>>(Xn, Xn, P2, nullptr, nullptr,
                1.f, 0.f, 0.f,
                1,0, 1,0, 1,0, 0,0, 0,0);
            cgemm64<<<grid, 256, 0, stream>>>(P2, Xn, P, Xn, P2,
                c3i, 1.f, c2,
                1,0, 1,0, 1,ts0, 1,0, 1,0);
        }

        u16* cur = P;
        u16* oth = CB;
        for (int n = 128; n > 1; n >>= 1) {
            cgemm64<<<dim3(4, 4, n/2), 256, 0, stream>>>(
                cur, cur, oth, cur, cur,
                1.f, 1.f, 1.f,
                2,1, 2,0, 1,0, 2,1, 2,0);
            u16* tmp = cur; cur = oth; oth = tmp;
        }
        final_kernel<<<1, 256, 0, stream>>>(cur, s0r, s0i, tgr, tgi,
                                            (float*)d_out, out_size);
    }
}